// Round 1
// 310.891 us; speedup vs baseline: 1.0184x; 1.0184x over previous
//
#include <hip/hip_runtime.h>

typedef __bf16 bf16;
typedef bf16 v8bf __attribute__((ext_vector_type(8)));
typedef bf16 v4bf __attribute__((ext_vector_type(4)));
typedef float v4f __attribute__((ext_vector_type(4)));
typedef float v16f __attribute__((ext_vector_type(16)));
typedef unsigned int u32;
typedef u32 v4u __attribute__((ext_vector_type(4)));

#define GAS __attribute__((address_space(1)))
#define LAS __attribute__((address_space(3)))

constexpr int D    = 1024;   // d_model
constexpr int ROWS = 8192;   // B*S
constexpr int TILE = 128;

// ---------------------------------------------------------------- cast ----
__global__ __launch_bounds__(256) void cast_all(
    const float* __restrict__ x,
    const float* __restrict__ wq, const float* __restrict__ wk,
    const float* __restrict__ wv, const float* __restrict__ wo,
    bf16* __restrict__ xb, bf16* __restrict__ wqb, bf16* __restrict__ wkb,
    bf16* __restrict__ wvb, bf16* __restrict__ wob)
{
    int i = blockIdx.x * 256 + threadIdx.x;
    const float* src; bf16* dst; int off;
    if (i < 2 * 1024 * 1024) { src = x; dst = xb; off = i; }
    else {
        int j = i - 2 * 1024 * 1024;
        int w = j >> 18;
        off = j & ((1 << 18) - 1);
        src = (w == 0) ? wq : (w == 1) ? wk : (w == 2) ? wv : wo;
        dst = (w == 0) ? wqb : (w == 1) ? wkb : (w == 2) ? wvb : wob;
    }
    float4 v = ((const float4*)src)[off];
    v4bf o;
    o[0] = (bf16)v.x; o[1] = (bf16)v.y; o[2] = (bf16)v.z; o[3] = (bf16)v.w;
    ((v4bf*)dst)[off] = o;
}

// ---------------------------------------------------------------- GEMM ----
// C = A (ROWS x D) * Bw^T. BK=64 as two stacked BK=32 panels (lds-DMA needs
// contiguity; fragment reads keep the conflict-free LD=32 pattern).
// MODE 0: bf16 out. z==0 (Q): scaled by 0.125*log2(e). z==2 (V): transposed
//         store into VtG[b][h][d][s]. MODE 1: fp32 out + bias + residual X.
template<int MODE>
__global__ __launch_bounds__(256) void gemm_bt(
    const bf16* __restrict__ A,
    const bf16* __restrict__ W0, const bf16* __restrict__ W1, const bf16* __restrict__ W2,
    bf16* __restrict__ O0, bf16* __restrict__ O1, bf16* __restrict__ O2,
    float* __restrict__ Of, const float* __restrict__ bias,
    const float* __restrict__ X)
{
    __shared__ bf16 As[2][TILE * 32];
    __shared__ bf16 Bs[2][TILE * 32];

    const int tid  = threadIdx.x;
    const int lane = tid & 63;
    const int wave = tid >> 6;
    const int quad = lane >> 4;
    const int l16  = lane & 15;
    const int wm   = (wave >> 1) * 64;
    const int wn   = (wave & 1) * 64;

    const int z = blockIdx.z;
    const bf16* Bw = (MODE == 0) ? ((z == 0) ? W0 : ((z == 1) ? W1 : W2)) : W0;
    bf16*       Ob = (MODE == 0) ? ((z == 0) ? O0 : ((z == 1) ? O1 : O2)) : O0;

    const long rowA0 = (long)blockIdx.y * TILE;
    const long rowB0 = (long)blockIdx.x * TILE;

    const int stRow = wave * 16 + (lane >> 2);
    const int stCol = (lane & 3) * 8;
    const bf16* gA = A  + (rowA0 + stRow) * D + stCol;
    const bf16* gB = Bw + (rowB0 + stRow) * D + stCol;
    const int ldsOff = wave * 16 * 32;

    const v4f vzero = {0.f, 0.f, 0.f, 0.f};
    v4f acc[4][4];
    #pragma unroll
    for (int i = 0; i < 4; i++)
        #pragma unroll
        for (int j = 0; j < 4; j++) acc[i][j] = vzero;

    for (int k0 = 0; k0 < D; k0 += 64) {
        __syncthreads();
        #pragma unroll
        for (int p = 0; p < 2; ++p)
            #pragma unroll
            for (int i = 0; i < 2; ++i) {
                __builtin_amdgcn_global_load_lds(
                    (const GAS void*)(gA + (long)i * 64 * D + p * 32),
                    (LAS void*)(&As[p][ldsOff + i * 64 * 32]), 16, 0, 0);
                __builtin_amdgcn_global_load_lds(
                    (const GAS void*)(gB + (long)i * 64 * D + p * 32),
                    (LAS void*)(&Bs[p][ldsOff + i * 64 * 32]), 16, 0, 0);
            }
        gA += 64; gB += 64;
        __syncthreads();

        #pragma unroll
        for (int p = 0; p < 2; ++p) {
            v8bf a[4], b[4];
            #pragma unroll
            for (int mi = 0; mi < 4; mi++)
                a[mi] = *(const v8bf*)(&As[p][(wm + mi * 16 + l16) * 32 + quad * 8]);
            #pragma unroll
            for (int ni = 0; ni < 4; ni++)
                b[ni] = *(const v8bf*)(&Bs[p][(wn + ni * 16 + l16) * 32 + quad * 8]);
            #pragma unroll
            for (int mi = 0; mi < 4; mi++)
                #pragma unroll
                for (int ni = 0; ni < 4; ni++)
                    acc[mi][ni] = __builtin_amdgcn_mfma_f32_16x16x32_bf16(a[mi], b[ni], acc[mi][ni], 0, 0, 0);
        }
    }

    const float qscale = 0.125f * 1.44269504f;

    if (MODE == 0 && z == 2) {
        #pragma unroll
        for (int mi = 0; mi < 4; mi++) {
            #pragma unroll
            for (int ni = 0; ni < 4; ni++) {
                const long col = rowB0 + wn + ni * 16 + l16;
                const long h_ = col >> 6, dd = col & 63;
                const long row0 = rowA0 + wm + mi * 16 + quad * 4;
                const long b_ = row0 >> 11, s0 = row0 & 2047;
                v4bf pk;
                #pragma unroll
                for (int r = 0; r < 4; r++) pk[r] = (bf16)acc[mi][ni][r];
                *(v4bf*)(Ob + ((b_ * 16 + h_) * 64 + dd) * 2048 + s0) = pk;
            }
        }
    } else {
        #pragma unroll
        for (int mi = 0; mi < 4; mi++) {
            #pragma unroll
            for (int ni = 0; ni < 4; ni++) {
                const long col = rowB0 + wn + ni * 16 + l16;
                float bv = (MODE == 1) ? bias[col] : 0.f;
                #pragma unroll
                for (int r = 0; r < 4; r++) {
                    const long row = rowA0 + wm + mi * 16 + quad * 4 + r;
                    float v = acc[mi][ni][r];
                    if (MODE == 1) Of[row * D + col] = v + bv + X[row * D + col];
                    else {
                        if (z == 0) v *= qscale;
                        Ob[row * D + col] = (bf16)v;
                    }
                }
            }
        }
    }
}

// ----------------------------------------------------------- attention ----
// grid (16 qtiles, 16 heads, 4 batch), 256 threads = 4 waves x 32 q-rows.
// 32x32x16 MFMA, swapped QK^T (S^T = K*Q^T) so each lane owns P for one
// q-row (col = lane&31). P transposed to the PV A-fragment IN REGISTERS:
// v_cvt_pk_bf16_f32 pairs + v_permlane32_swap_b32 (dst.upper <-> src.lower):
//   swap(a0,b0): a0' = [a0.lo|b0.lo] = W0, b0' = [a0.hi|b0.hi] = W2.
// No P LDS round-trip. K/V LDS tiles are [64][64] with XOR swizzle
// (16B-chunk ^= row&7) so the 32-lane same-column b128 reads are
// conflict-free. Fixed-max softmax with raw exp2 (scores bounded; Q
// pre-scaled by 0.125*log2e in the QKV GEMM).
__global__ __launch_bounds__(256) void attn_kernel(
    const bf16* __restrict__ Q, const bf16* __restrict__ Kg,
    const bf16* __restrict__ VtG, bf16* __restrict__ O)
{
    const int qt = blockIdx.x, h = blockIdx.y, b = blockIdx.z;
    const int tid  = threadIdx.x;
    const int lane = tid & 63;
    const int wave = tid >> 6;
    const int l31  = lane & 31;
    const int hi   = lane >> 5;

    __shared__ bf16 Kt[64 * 64];   // K[kk][d], swizzled
    __shared__ bf16 Vt[64 * 64];   // V^T[d][kk], swizzled

    // Q B-fragments, resident whole kernel: lane holds Q[q=l31][d=f*16+hi*8+j]
    const long qrow = (long)(b * 2048 + qt * 128 + wave * 32 + l31);
    v8bf qB[4];
    #pragma unroll
    for (int f = 0; f < 4; f++)
        qB[f] = *(const v8bf*)(Q + qrow * D + h * 64 + f * 16 + hi * 8);

    v16f o_acc[2];
    #pragma unroll
    for (int d2 = 0; d2 < 2; d2++)
        #pragma unroll
        for (int i = 0; i < 16; i++) o_acc[d2][i] = 0.f;
    float l_acc = 0.f;

    const int iR = tid >> 3;        // staging row 0..31 (and +32)
    const int c8 = tid & 7;         // 16B chunk 0..7
    const int sC = c8 * 8;
    const bf16* kLane = Kg  + (long)b * 2048 * D + h * 64 + sC + (long)iR * D;
    const bf16* vLane = VtG + (long)(b * 16 + h) * 64 * 2048 + sC + (long)iR * 2048;
    const int wOff = iR * 64 + ((c8 ^ (iR & 7)) * 8);   // swizzled write slot
    bf16* ktW = Kt + wOff;
    bf16* vtW = Vt + wOff;

    v8bf kpre[2], vpre[2];
    kpre[0] = *(const v8bf*)(kLane);
    kpre[1] = *(const v8bf*)(kLane + 32 * D);
    vpre[0] = *(const v8bf*)(vLane);
    vpre[1] = *(const v8bf*)(vLane + 32 * 2048);
    kLane += 64 * D;
    vLane += 64;

    for (int kt = 0; kt < 32; ++kt) {
        __syncthreads();
        *(v8bf*)(ktW)            = kpre[0];
        *(v8bf*)(ktW + 32 * 64)  = kpre[1];
        *(v8bf*)(vtW)            = vpre[0];
        *(v8bf*)(vtW + 32 * 64)  = vpre[1];
        __syncthreads();

        if (kt + 1 < 32) {
            kpre[0] = *(const v8bf*)(kLane);
            kpre[1] = *(const v8bf*)(kLane + 32 * D);
            vpre[0] = *(const v8bf*)(vLane);
            vpre[1] = *(const v8bf*)(vLane + 32 * 2048);
            kLane += 64 * D;
            vLane += 64;
        }

        #pragma unroll
        for (int ko = 0; ko < 2; ko++) {
            // S^T (32k x 32q) = K_sub * Q^T, contraction d=64 in 4 steps
            v16f st;
            #pragma unroll
            for (int i = 0; i < 16; i++) st[i] = 0.f;
            const int krow = ko * 32 + l31;
            const int ksw  = krow & 7;
            #pragma unroll
            for (int f = 0; f < 4; f++) {
                v8bf kA = *(const v8bf*)(Kt + krow * 64 + (((2 * f + hi) ^ ksw) * 8));
                st = __builtin_amdgcn_mfma_f32_32x32x16_bf16(kA, qB[f], st, 0, 0, 0);
            }

            // p = exp2(s); accumulate l in f32 (same math as previous version)
            float p[16];
            #pragma unroll
            for (int r = 0; r < 16; r++) {
                p[r] = __builtin_amdgcn_exp2f(st[r]);
                l_acc += p[r];
            }

            // in-register transpose to PV A-frags + PV MFMA
            #pragma unroll
            for (int u = 0; u < 2; u++) {
                const int s = ko * 2 + u;          // k-step of 16 within tile
                u32 a0, a1, b0, b1;
                asm("v_cvt_pk_bf16_f32 %0, %1, %2" : "=v"(a0) : "v"(p[u*8+0]), "v"(p[u*8+1]));
                asm("v_cvt_pk_bf16_f32 %0, %1, %2" : "=v"(a1) : "v"(p[u*8+2]), "v"(p[u*8+3]));
                asm("v_cvt_pk_bf16_f32 %0, %1, %2" : "=v"(b0) : "v"(p[u*8+4]), "v"(p[u*8+5]));
                asm("v_cvt_pk_bf16_f32 %0, %1, %2" : "=v"(b1) : "v"(p[u*8+6]), "v"(p[u*8+7]));
                asm("v_permlane32_swap_b32 %0, %1" : "+v"(a0), "+v"(b0));
                asm("v_permlane32_swap_b32 %0, %1" : "+v"(a1), "+v"(b1));
                v4u w; w[0] = a0; w[1] = a1; w[2] = b0; w[3] = b1;
                const v8bf pa = __builtin_bit_cast(v8bf, w);
                #pragma unroll
                for (int d2 = 0; d2 < 2; d2++) {
                    const int vrow = d2 * 32 + l31;
                    v8bf vb = *(const v8bf*)(Vt + vrow * 64 + (((2 * s + hi) ^ (vrow & 7)) * 8));
                    o_acc[d2] = __builtin_amdgcn_mfma_f32_32x32x16_bf16(pa, vb, o_acc[d2], 0, 0, 0);
                }
            }
        }
    }

    // l per q-row: lane (l31,hi) holds the hi-half partial; combine halves.
    l_acc += __shfl_xor(l_acc, 32);

    const long obase = (long)(b * 2048 + qt * 128 + wave * 32);
    #pragma unroll
    for (int r = 0; r < 16; r++) {
        const int qp = (r & 3) + 8 * (r >> 2) + 4 * hi;   // C row for reg r
        const float inv = 1.f / __shfl(l_acc, qp);
        O[(obase + qp) * D + h * 64 + l31]      = (bf16)(o_acc[0][r] * inv);
        O[(obase + qp) * D + h * 64 + 32 + l31] = (bf16)(o_acc[1][r] * inv);
    }
}

// ------------------------------------------------------------------ LN ----
__global__ __launch_bounds__(256) void ln_kernel(
    const float* __restrict__ g, const float* __restrict__ beta,
    float* __restrict__ out)
{
    const int row = blockIdx.x;
    const int t = threadIdx.x;
    const int lane = t & 63, wave = t >> 6;
    const long base = (long)row * D + t * 4;

    float4 yv = *(const float4*)(out + base);
    float y0 = yv.x, y1 = yv.y, y2 = yv.z, y3 = yv.w;
    float s1 = y0 + y1 + y2 + y3;
    float s2 = y0*y0 + y1*y1 + y2*y2 + y3*y3;
    #pragma unroll
    for (int off = 1; off < 64; off <<= 1) {
        s1 += __shfl_xor(s1, off);
        s2 += __shfl_xor(s2, off);
    }
    __shared__ float r1[4], r2[4];
    if (lane == 0) { r1[wave] = s1; r2[wave] = s2; }
    __syncthreads();
    float S1 = r1[0] + r1[1] + r1[2] + r1[3];
    float S2 = r2[0] + r2[1] + r2[2] + r2[3];
    float mu  = S1 * (1.f / 1024.f);
    float var = S2 * (1.f / 1024.f) - mu * mu;
    float rsd = rsqrtf(var + 1e-5f);

    float4 gv = *(const float4*)(g + t * 4);
    float4 bv = *(const float4*)(beta + t * 4);
    float4 o;
    o.x = (y0 - mu) * rsd * gv.x + bv.x;
    o.y = (y1 - mu) * rsd * gv.y + bv.y;
    o.z = (y2 - mu) * rsd * gv.z + bv.z;
    o.w = (y3 - mu) * rsd * gv.w + bv.w;
    *(float4*)(out + base) = o;
}

// ---------------------------------------------------------------- launch --
extern "C" void kernel_launch(void* const* d_in, const int* in_sizes, int n_in,
                              void* d_out, int out_size, void* d_ws, size_t ws_size,
                              hipStream_t stream)
{
    const float* x   = (const float*)d_in[0];
    const float* wq  = (const float*)d_in[1];
    const float* wk  = (const float*)d_in[2];
    const float* wv  = (const float*)d_in[3];
    const float* wo  = (const float*)d_in[4];
    const float* bo  = (const float*)d_in[5];
    const float* lng = (const float*)d_in[6];
    const float* lnb = (const float*)d_in[7];
    float* out = (float*)d_out;

    char* ws = (char*)d_ws;
    bf16* xb  = (bf16*)(ws);                            // 16 MiB
    bf16* wqb = (bf16*)(ws + (size_t)16 * 1024 * 1024); // 4 x 2 MiB
    bf16* wkb = wqb + 1024 * 1024;
    bf16* wvb = wkb + 1024 * 1024;
    bf16* wob = wvb + 1024 * 1024;
    bf16* Qb  = (bf16*)(ws + (size_t)24 * 1024 * 1024); // 4 x 16 MiB
    bf16* Kb  = Qb + (size_t)ROWS * D;
    bf16* VtG = Kb + (size_t)ROWS * D;                  // V transposed [b][h][d][s]
    bf16* Ab  = VtG + (size_t)ROWS * D;                 // total 88 MiB

    cast_all<<<12288, 256, 0, stream>>>(x, wq, wk, wv, wo,
                                        xb, wqb, wkb, wvb, wob);

    dim3 gqkv(D / TILE, ROWS / TILE, 3);
    gemm_bt<0><<<gqkv, 256, 0, stream>>>(xb, wqb, wkb, wvb, Qb, Kb, VtG,
                                         nullptr, nullptr, nullptr);

    attn_kernel<<<dim3(16, 16, 4), 256, 0, stream>>>(Qb, Kb, VtG, Ab);

    dim3 gout(D / TILE, ROWS / TILE, 1);
    gemm_bt<1><<<gout, 256, 0, stream>>>(Ab, wob, nullptr, nullptr,
                                         nullptr, nullptr, nullptr, out, bo, x);

    ln_kernel<<<8192, 256, 0, stream>>>(lng, lnb, out);
}

// Round 2
// 299.870 us; speedup vs baseline: 1.0558x; 1.0368x over previous
//
#include <hip/hip_runtime.h>

typedef __bf16 bf16;
typedef bf16 v8bf __attribute__((ext_vector_type(8)));
typedef bf16 v4bf __attribute__((ext_vector_type(4)));
typedef float v4f __attribute__((ext_vector_type(4)));
typedef float v16f __attribute__((ext_vector_type(16)));
typedef unsigned int u32;
typedef u32 v4u __attribute__((ext_vector_type(4)));

#define GAS __attribute__((address_space(1)))
#define LAS __attribute__((address_space(3)))

constexpr int D    = 1024;   // d_model
constexpr int ROWS = 8192;   // B*S
constexpr int TILE = 128;

// ---------------------------------------------------------------- cast ----
__global__ __launch_bounds__(256) void cast_all(
    const float* __restrict__ x,
    const float* __restrict__ wq, const float* __restrict__ wk,
    const float* __restrict__ wv, const float* __restrict__ wo,
    bf16* __restrict__ xb, bf16* __restrict__ wqb, bf16* __restrict__ wkb,
    bf16* __restrict__ wvb, bf16* __restrict__ wob)
{
    int i = blockIdx.x * 256 + threadIdx.x;
    const float* src; bf16* dst; int off;
    if (i < 2 * 1024 * 1024) { src = x; dst = xb; off = i; }
    else {
        int j = i - 2 * 1024 * 1024;
        int w = j >> 18;
        off = j & ((1 << 18) - 1);
        src = (w == 0) ? wq : (w == 1) ? wk : (w == 2) ? wv : wo;
        dst = (w == 0) ? wqb : (w == 1) ? wkb : (w == 2) ? wvb : wob;
    }
    float4 v = ((const float4*)src)[off];
    v4bf o;
    o[0] = (bf16)v.x; o[1] = (bf16)v.y; o[2] = (bf16)v.z; o[3] = (bf16)v.w;
    ((v4bf*)dst)[off] = o;
}

// ---------------------------------------------------------------- GEMM ----
// C = A (ROWS x D) * Bw^T. BK=64 as two stacked BK=32 panels (lds-DMA needs
// contiguity; fragment reads keep the conflict-free LD=32 pattern).
// MODE 0: bf16 out. z==0 (Q): scaled by 0.125*log2(e). z==2 (V): transposed
//         store into VtG[b][h][d][s]. MODE 1: fp32 out + bias + residual X.
template<int MODE>
__global__ __launch_bounds__(256) void gemm_bt(
    const bf16* __restrict__ A,
    const bf16* __restrict__ W0, const bf16* __restrict__ W1, const bf16* __restrict__ W2,
    bf16* __restrict__ O0, bf16* __restrict__ O1, bf16* __restrict__ O2,
    float* __restrict__ Of, const float* __restrict__ bias,
    const float* __restrict__ X)
{
    __shared__ bf16 As[2][TILE * 32];
    __shared__ bf16 Bs[2][TILE * 32];

    const int tid  = threadIdx.x;
    const int lane = tid & 63;
    const int wave = tid >> 6;
    const int quad = lane >> 4;
    const int l16  = lane & 15;
    const int wm   = (wave >> 1) * 64;
    const int wn   = (wave & 1) * 64;

    const int z = blockIdx.z;
    const bf16* Bw = (MODE == 0) ? ((z == 0) ? W0 : ((z == 1) ? W1 : W2)) : W0;
    bf16*       Ob = (MODE == 0) ? ((z == 0) ? O0 : ((z == 1) ? O1 : O2)) : O0;

    const long rowA0 = (long)blockIdx.y * TILE;
    const long rowB0 = (long)blockIdx.x * TILE;

    const int stRow = wave * 16 + (lane >> 2);
    const int stCol = (lane & 3) * 8;
    const bf16* gA = A  + (rowA0 + stRow) * D + stCol;
    const bf16* gB = Bw + (rowB0 + stRow) * D + stCol;
    const int ldsOff = wave * 16 * 32;

    const v4f vzero = {0.f, 0.f, 0.f, 0.f};
    v4f acc[4][4];
    #pragma unroll
    for (int i = 0; i < 4; i++)
        #pragma unroll
        for (int j = 0; j < 4; j++) acc[i][j] = vzero;

    for (int k0 = 0; k0 < D; k0 += 64) {
        __syncthreads();
        #pragma unroll
        for (int p = 0; p < 2; ++p)
            #pragma unroll
            for (int i = 0; i < 2; ++i) {
                __builtin_amdgcn_global_load_lds(
                    (const GAS void*)(gA + (long)i * 64 * D + p * 32),
                    (LAS void*)(&As[p][ldsOff + i * 64 * 32]), 16, 0, 0);
                __builtin_amdgcn_global_load_lds(
                    (const GAS void*)(gB + (long)i * 64 * D + p * 32),
                    (LAS void*)(&Bs[p][ldsOff + i * 64 * 32]), 16, 0, 0);
            }
        gA += 64; gB += 64;
        __syncthreads();

        #pragma unroll
        for (int p = 0; p < 2; ++p) {
            v8bf a[4], b[4];
            #pragma unroll
            for (int mi = 0; mi < 4; mi++)
                a[mi] = *(const v8bf*)(&As[p][(wm + mi * 16 + l16) * 32 + quad * 8]);
            #pragma unroll
            for (int ni = 0; ni < 4; ni++)
                b[ni] = *(const v8bf*)(&Bs[p][(wn + ni * 16 + l16) * 32 + quad * 8]);
            #pragma unroll
            for (int mi = 0; mi < 4; mi++)
                #pragma unroll
                for (int ni = 0; ni < 4; ni++)
                    acc[mi][ni] = __builtin_amdgcn_mfma_f32_16x16x32_bf16(a[mi], b[ni], acc[mi][ni], 0, 0, 0);
        }
    }

    const float qscale = 0.125f * 1.44269504f;

    if (MODE == 0 && z == 2) {
        #pragma unroll
        for (int mi = 0; mi < 4; mi++) {
            #pragma unroll
            for (int ni = 0; ni < 4; ni++) {
                const long col = rowB0 + wn + ni * 16 + l16;
                const long h_ = col >> 6, dd = col & 63;
                const long row0 = rowA0 + wm + mi * 16 + quad * 4;
                const long b_ = row0 >> 11, s0 = row0 & 2047;
                v4bf pk;
                #pragma unroll
                for (int r = 0; r < 4; r++) pk[r] = (bf16)acc[mi][ni][r];
                *(v4bf*)(Ob + ((b_ * 16 + h_) * 64 + dd) * 2048 + s0) = pk;
            }
        }
    } else {
        #pragma unroll
        for (int mi = 0; mi < 4; mi++) {
            #pragma unroll
            for (int ni = 0; ni < 4; ni++) {
                const long col = rowB0 + wn + ni * 16 + l16;
                float bv = (MODE == 1) ? bias[col] : 0.f;
                #pragma unroll
                for (int r = 0; r < 4; r++) {
                    const long row = rowA0 + wm + mi * 16 + quad * 4 + r;
                    float v = acc[mi][ni][r];
                    if (MODE == 1) Of[row * D + col] = v + bv + X[row * D + col];
                    else {
                        if (z == 0) v *= qscale;
                        Ob[row * D + col] = (bf16)v;
                    }
                }
            }
        }
    }
}

// ----------------------------------------------------------- attention ----
// 1024 blocks (XCD-grouped decode), 256 threads = 4 waves x 32 q-rows.
// 32x32x16 MFMA, swapped QK^T, in-register P transpose (cvt_pk+permlane).
// K/V LDS double-buffered: ONE barrier per k-tile; ds_writes of the next
// tile and global loads for tile+2 overlap the current tile's compute.
// XOR-swizzled LDS (16B-chunk ^= row&7) keeps all b128 reads conflict-free.
__global__ __launch_bounds__(256) void attn_kernel(
    const bf16* __restrict__ Q, const bf16* __restrict__ Kg,
    const bf16* __restrict__ VtG, bf16* __restrict__ O)
{
    // 64 (h,b) groups x 16 q-tiles; put all q-tiles of a group on one XCD
    // (linear blockIdx round-robins XCDs: xcd = id & 7).
    const int id  = blockIdx.x;
    const int xcd = id & 7, j = id >> 3;
    const int qt  = j & 15;
    const int g   = xcd + 8 * (j >> 4);
    const int h   = g & 15, b = g >> 4;

    const int tid  = threadIdx.x;
    const int lane = tid & 63;
    const int wave = tid >> 6;
    const int l31  = lane & 31;
    const int hi   = lane >> 5;

    __shared__ bf16 Kt[2][64 * 64];   // K[kk][d], swizzled
    __shared__ bf16 Vt[2][64 * 64];   // V^T[d][kk], swizzled

    // Q B-fragments, resident whole kernel: lane holds Q[q=l31][d=f*16+hi*8+j]
    const long qrow = (long)(b * 2048 + qt * 128 + wave * 32 + l31);
    v8bf qB[4];
    #pragma unroll
    for (int f = 0; f < 4; f++)
        qB[f] = *(const v8bf*)(Q + qrow * D + h * 64 + f * 16 + hi * 8);

    const v16f z16 = {0.f,0.f,0.f,0.f,0.f,0.f,0.f,0.f,
                      0.f,0.f,0.f,0.f,0.f,0.f,0.f,0.f};
    v16f o_acc[2];
    o_acc[0] = z16; o_acc[1] = z16;
    float l0 = 0.f, l1 = 0.f;

    const int iR = tid >> 3;        // staging row 0..31 (and +32)
    const int c8 = tid & 7;         // 16B chunk 0..7
    const int sC = c8 * 8;
    const bf16* kLane = Kg  + (long)b * 2048 * D + h * 64 + sC + (long)iR * D;
    const bf16* vLane = VtG + (long)(b * 16 + h) * 64 * 2048 + sC + (long)iR * 2048;
    const int wOff = iR * 64 + ((c8 ^ (iR & 7)) * 8);   // swizzled write slot

    v8bf kpre[2], vpre[2];
    // tile 0 -> regs -> buf0
    kpre[0] = *(const v8bf*)(kLane);
    kpre[1] = *(const v8bf*)(kLane + 32 * D);
    vpre[0] = *(const v8bf*)(vLane);
    vpre[1] = *(const v8bf*)(vLane + 32 * 2048);
    kLane += 64 * D; vLane += 64;
    *(v8bf*)(&Kt[0][wOff])           = kpre[0];
    *(v8bf*)(&Kt[0][wOff + 32 * 64]) = kpre[1];
    *(v8bf*)(&Vt[0][wOff])           = vpre[0];
    *(v8bf*)(&Vt[0][wOff + 32 * 64]) = vpre[1];
    // tile 1 -> regs
    kpre[0] = *(const v8bf*)(kLane);
    kpre[1] = *(const v8bf*)(kLane + 32 * D);
    vpre[0] = *(const v8bf*)(vLane);
    vpre[1] = *(const v8bf*)(vLane + 32 * 2048);
    kLane += 64 * D; vLane += 64;

    for (int kt = 0; kt < 32; ++kt) {
        const int cur = kt & 1;
        __syncthreads();   // buf[cur] ready; prior reads of buf[cur^1] done

        // stage tile kt+1 into buf[cur^1] (overlaps compute below)
        if (kt + 1 < 32) {
            *(v8bf*)(&Kt[cur ^ 1][wOff])           = kpre[0];
            *(v8bf*)(&Kt[cur ^ 1][wOff + 32 * 64]) = kpre[1];
            *(v8bf*)(&Vt[cur ^ 1][wOff])           = vpre[0];
            *(v8bf*)(&Vt[cur ^ 1][wOff + 32 * 64]) = vpre[1];
        }
        // issue loads for tile kt+2 (latency hidden under this compute)
        if (kt + 2 < 32) {
            kpre[0] = *(const v8bf*)(kLane);
            kpre[1] = *(const v8bf*)(kLane + 32 * D);
            vpre[0] = *(const v8bf*)(vLane);
            vpre[1] = *(const v8bf*)(vLane + 32 * 2048);
            kLane += 64 * D; vLane += 64;
        }

        #pragma unroll
        for (int ko = 0; ko < 2; ko++) {
            // S^T (32k x 32q) = K_sub * Q^T, contraction d=64 in 4 steps
            const int krow = ko * 32 + l31;
            const int ksw  = krow & 7;
            v8bf kA0 = *(const v8bf*)(&Kt[cur][krow * 64 + (((0 + hi) ^ ksw) * 8)]);
            v16f st  = __builtin_amdgcn_mfma_f32_32x32x16_bf16(kA0, qB[0], z16, 0, 0, 0);
            #pragma unroll
            for (int f = 1; f < 4; f++) {
                v8bf kA = *(const v8bf*)(&Kt[cur][krow * 64 + (((2 * f + hi) ^ ksw) * 8)]);
                st = __builtin_amdgcn_mfma_f32_32x32x16_bf16(kA, qB[f], st, 0, 0, 0);
            }

            // p = exp2(s); accumulate l in two chains
            float p[16];
            #pragma unroll
            for (int r = 0; r < 16; r++) {
                p[r] = __builtin_amdgcn_exp2f(st[r]);
                if (r & 1) l1 += p[r]; else l0 += p[r];
            }

            // in-register transpose to PV A-frags + PV MFMA
            #pragma unroll
            for (int u = 0; u < 2; u++) {
                const int s = ko * 2 + u;          // k-step of 16 within tile
                u32 a0, a1, b0, b1;
                asm("v_cvt_pk_bf16_f32 %0, %1, %2" : "=v"(a0) : "v"(p[u*8+0]), "v"(p[u*8+1]));
                asm("v_cvt_pk_bf16_f32 %0, %1, %2" : "=v"(a1) : "v"(p[u*8+2]), "v"(p[u*8+3]));
                asm("v_cvt_pk_bf16_f32 %0, %1, %2" : "=v"(b0) : "v"(p[u*8+4]), "v"(p[u*8+5]));
                asm("v_cvt_pk_bf16_f32 %0, %1, %2" : "=v"(b1) : "v"(p[u*8+6]), "v"(p[u*8+7]));
                asm("v_permlane32_swap_b32 %0, %1" : "+v"(a0), "+v"(b0));
                asm("v_permlane32_swap_b32 %0, %1" : "+v"(a1), "+v"(b1));
                v4u w; w[0] = a0; w[1] = a1; w[2] = b0; w[3] = b1;
                const v8bf pa = __builtin_bit_cast(v8bf, w);
                #pragma unroll
                for (int d2 = 0; d2 < 2; d2++) {
                    const int vrow = d2 * 32 + l31;
                    v8bf vb = *(const v8bf*)(&Vt[cur][vrow * 64 + (((2 * s + hi) ^ (vrow & 7)) * 8)]);
                    o_acc[d2] = __builtin_amdgcn_mfma_f32_32x32x16_bf16(pa, vb, o_acc[d2], 0, 0, 0);
                }
            }
        }
    }

    // l per q-row: lane (l31,hi) holds the hi-half partial; combine halves.
    float l_acc = l0 + l1;
    l_acc += __shfl_xor(l_acc, 32);

    const long obase = (long)(b * 2048 + qt * 128 + wave * 32);
    #pragma unroll
    for (int r = 0; r < 16; r++) {
        const int qp = (r & 3) + 8 * (r >> 2) + 4 * hi;   // C row for reg r
        const float inv = 1.f / __shfl(l_acc, qp);
        O[(obase + qp) * D + h * 64 + l31]      = (bf16)(o_acc[0][r] * inv);
        O[(obase + qp) * D + h * 64 + 32 + l31] = (bf16)(o_acc[1][r] * inv);
    }
}

// ------------------------------------------------------------------ LN ----
__global__ __launch_bounds__(256) void ln_kernel(
    const float* __restrict__ g, const float* __restrict__ beta,
    float* __restrict__ out)
{
    const int row = blockIdx.x;
    const int t = threadIdx.x;
    const int lane = t & 63, wave = t >> 6;
    const long base = (long)row * D + t * 4;

    float4 yv = *(const float4*)(out + base);
    float y0 = yv.x, y1 = yv.y, y2 = yv.z, y3 = yv.w;
    float s1 = y0 + y1 + y2 + y3;
    float s2 = y0*y0 + y1*y1 + y2*y2 + y3*y3;
    #pragma unroll
    for (int off = 1; off < 64; off <<= 1) {
        s1 += __shfl_xor(s1, off);
        s2 += __shfl_xor(s2, off);
    }
    __shared__ float r1[4], r2[4];
    if (lane == 0) { r1[wave] = s1; r2[wave] = s2; }
    __syncthreads();
    float S1 = r1[0] + r1[1] + r1[2] + r1[3];
    float S2 = r2[0] + r2[1] + r2[2] + r2[3];
    float mu  = S1 * (1.f / 1024.f);
    float var = S2 * (1.f / 1024.f) - mu * mu;
    float rsd = rsqrtf(var + 1e-5f);

    float4 gv = *(const float4*)(g + t * 4);
    float4 bv = *(const float4*)(beta + t * 4);
    float4 o;
    o.x = (y0 - mu) * rsd * gv.x + bv.x;
    o.y = (y1 - mu) * rsd * gv.y + bv.y;
    o.z = (y2 - mu) * rsd * gv.z + bv.z;
    o.w = (y3 - mu) * rsd * gv.w + bv.w;
    *(float4*)(out + base) = o;
}

// ---------------------------------------------------------------- launch --
extern "C" void kernel_launch(void* const* d_in, const int* in_sizes, int n_in,
                              void* d_out, int out_size, void* d_ws, size_t ws_size,
                              hipStream_t stream)
{
    const float* x   = (const float*)d_in[0];
    const float* wq  = (const float*)d_in[1];
    const float* wk  = (const float*)d_in[2];
    const float* wv  = (const float*)d_in[3];
    const float* wo  = (const float*)d_in[4];
    const float* bo  = (const float*)d_in[5];
    const float* lng = (const float*)d_in[6];
    const float* lnb = (const float*)d_in[7];
    float* out = (float*)d_out;

    char* ws = (char*)d_ws;
    bf16* xb  = (bf16*)(ws);                            // 16 MiB
    bf16* wqb = (bf16*)(ws + (size_t)16 * 1024 * 1024); // 4 x 2 MiB
    bf16* wkb = wqb + 1024 * 1024;
    bf16* wvb = wkb + 1024 * 1024;
    bf16* wob = wvb + 1024 * 1024;
    bf16* Qb  = (bf16*)(ws + (size_t)24 * 1024 * 1024); // 4 x 16 MiB
    bf16* Kb  = Qb + (size_t)ROWS * D;
    bf16* VtG = Kb + (size_t)ROWS * D;                  // V transposed [b][h][d][s]
    bf16* Ab  = VtG + (size_t)ROWS * D;                 // total 88 MiB

    cast_all<<<12288, 256, 0, stream>>>(x, wq, wk, wv, wo,
                                        xb, wqb, wkb, wvb, wob);

    dim3 gqkv(D / TILE, ROWS / TILE, 3);
    gemm_bt<0><<<gqkv, 256, 0, stream>>>(xb, wqb, wkb, wvb, Qb, Kb, VtG,
                                         nullptr, nullptr, nullptr);

    attn_kernel<<<dim3(1024, 1, 1), 256, 0, stream>>>(Qb, Kb, VtG, Ab);

    dim3 gout(D / TILE, ROWS / TILE, 1);
    gemm_bt<1><<<gout, 256, 0, stream>>>(Ab, wob, nullptr, nullptr,
                                         nullptr, nullptr, nullptr, out, bo, x);

    ln_kernel<<<8192, 256, 0, stream>>>(lng, lnb, out);
}

// Round 3
// 298.893 us; speedup vs baseline: 1.0593x; 1.0033x over previous
//
#include <hip/hip_runtime.h>

typedef __bf16 bf16;
typedef bf16 v8bf __attribute__((ext_vector_type(8)));
typedef bf16 v4bf __attribute__((ext_vector_type(4)));
typedef float v4f __attribute__((ext_vector_type(4)));
typedef float v16f __attribute__((ext_vector_type(16)));
typedef unsigned int u32;
typedef u32 v4u __attribute__((ext_vector_type(4)));

#define GAS __attribute__((address_space(1)))
#define LAS __attribute__((address_space(3)))

constexpr int D    = 1024;   // d_model
constexpr int ROWS = 8192;   // B*S
constexpr int TILE = 128;

// ---------------------------------------------------------------- cast ----
__global__ __launch_bounds__(256) void cast_all(
    const float* __restrict__ x,
    const float* __restrict__ wq, const float* __restrict__ wk,
    const float* __restrict__ wv, const float* __restrict__ wo,
    bf16* __restrict__ xb, bf16* __restrict__ wqb, bf16* __restrict__ wkb,
    bf16* __restrict__ wvb, bf16* __restrict__ wob)
{
    int i = blockIdx.x * 256 + threadIdx.x;
    const float* src; bf16* dst; int off;
    if (i < 2 * 1024 * 1024) { src = x; dst = xb; off = i; }
    else {
        int j = i - 2 * 1024 * 1024;
        int w = j >> 18;
        off = j & ((1 << 18) - 1);
        src = (w == 0) ? wq : (w == 1) ? wk : (w == 2) ? wv : wo;
        dst = (w == 0) ? wqb : (w == 1) ? wkb : (w == 2) ? wvb : wob;
    }
    float4 v = ((const float4*)src)[off];
    v4bf o;
    o[0] = (bf16)v.x; o[1] = (bf16)v.y; o[2] = (bf16)v.z; o[3] = (bf16)v.w;
    ((v4bf*)dst)[off] = o;
}

// ---------------------------------------------------------------- GEMM ----
// C = A (ROWS x D) * Bw^T. BK=64 as two stacked BK=32 panels (lds-DMA needs
// contiguity; fragment reads keep the conflict-free LD=32 pattern).
// MODE 0: bf16 out. z==0 (Q): scaled by 0.125*log2(e). z==2 (V): transposed
//         store into VtG[b][h][d][s]. MODE 1: fp32 out + bias + residual X.
template<int MODE>
__global__ __launch_bounds__(256) void gemm_bt(
    const bf16* __restrict__ A,
    const bf16* __restrict__ W0, const bf16* __restrict__ W1, const bf16* __restrict__ W2,
    bf16* __restrict__ O0, bf16* __restrict__ O1, bf16* __restrict__ O2,
    float* __restrict__ Of, const float* __restrict__ bias,
    const float* __restrict__ X)
{
    __shared__ bf16 As[2][TILE * 32];
    __shared__ bf16 Bs[2][TILE * 32];

    const int tid  = threadIdx.x;
    const int lane = tid & 63;
    const int wave = tid >> 6;
    const int quad = lane >> 4;
    const int l16  = lane & 15;
    const int wm   = (wave >> 1) * 64;
    const int wn   = (wave & 1) * 64;

    const int z = blockIdx.z;
    const bf16* Bw = (MODE == 0) ? ((z == 0) ? W0 : ((z == 1) ? W1 : W2)) : W0;
    bf16*       Ob = (MODE == 0) ? ((z == 0) ? O0 : ((z == 1) ? O1 : O2)) : O0;

    const long rowA0 = (long)blockIdx.y * TILE;
    const long rowB0 = (long)blockIdx.x * TILE;

    const int stRow = wave * 16 + (lane >> 2);
    const int stCol = (lane & 3) * 8;
    const bf16* gA = A  + (rowA0 + stRow) * D + stCol;
    const bf16* gB = Bw + (rowB0 + stRow) * D + stCol;
    const int ldsOff = wave * 16 * 32;

    const v4f vzero = {0.f, 0.f, 0.f, 0.f};
    v4f acc[4][4];
    #pragma unroll
    for (int i = 0; i < 4; i++)
        #pragma unroll
        for (int j = 0; j < 4; j++) acc[i][j] = vzero;

    for (int k0 = 0; k0 < D; k0 += 64) {
        __syncthreads();
        #pragma unroll
        for (int p = 0; p < 2; ++p)
            #pragma unroll
            for (int i = 0; i < 2; ++i) {
                __builtin_amdgcn_global_load_lds(
                    (const GAS void*)(gA + (long)i * 64 * D + p * 32),
                    (LAS void*)(&As[p][ldsOff + i * 64 * 32]), 16, 0, 0);
                __builtin_amdgcn_global_load_lds(
                    (const GAS void*)(gB + (long)i * 64 * D + p * 32),
                    (LAS void*)(&Bs[p][ldsOff + i * 64 * 32]), 16, 0, 0);
            }
        gA += 64; gB += 64;
        __syncthreads();

        #pragma unroll
        for (int p = 0; p < 2; ++p) {
            v8bf a[4], b[4];
            #pragma unroll
            for (int mi = 0; mi < 4; mi++)
                a[mi] = *(const v8bf*)(&As[p][(wm + mi * 16 + l16) * 32 + quad * 8]);
            #pragma unroll
            for (int ni = 0; ni < 4; ni++)
                b[ni] = *(const v8bf*)(&Bs[p][(wn + ni * 16 + l16) * 32 + quad * 8]);
            #pragma unroll
            for (int mi = 0; mi < 4; mi++)
                #pragma unroll
                for (int ni = 0; ni < 4; ni++)
                    acc[mi][ni] = __builtin_amdgcn_mfma_f32_16x16x32_bf16(a[mi], b[ni], acc[mi][ni], 0, 0, 0);
        }
    }

    const float qscale = 0.125f * 1.44269504f;

    if (MODE == 0 && z == 2) {
        #pragma unroll
        for (int mi = 0; mi < 4; mi++) {
            #pragma unroll
            for (int ni = 0; ni < 4; ni++) {
                const long col = rowB0 + wn + ni * 16 + l16;
                const long h_ = col >> 6, dd = col & 63;
                const long row0 = rowA0 + wm + mi * 16 + quad * 4;
                const long b_ = row0 >> 11, s0 = row0 & 2047;
                v4bf pk;
                #pragma unroll
                for (int r = 0; r < 4; r++) pk[r] = (bf16)acc[mi][ni][r];
                *(v4bf*)(Ob + ((b_ * 16 + h_) * 64 + dd) * 2048 + s0) = pk;
            }
        }
    } else {
        #pragma unroll
        for (int mi = 0; mi < 4; mi++) {
            #pragma unroll
            for (int ni = 0; ni < 4; ni++) {
                const long col = rowB0 + wn + ni * 16 + l16;
                float bv = (MODE == 1) ? bias[col] : 0.f;
                #pragma unroll
                for (int r = 0; r < 4; r++) {
                    const long row = rowA0 + wm + mi * 16 + quad * 4 + r;
                    float v = acc[mi][ni][r];
                    if (MODE == 1) Of[row * D + col] = v + bv + X[row * D + col];
                    else {
                        if (z == 0) v *= qscale;
                        Ob[row * D + col] = (bf16)v;
                    }
                }
            }
        }
    }
}

// ----------------------------------------------------------- attention ----
// 512 blocks (XCD-grouped decode), 512 threads = 8 waves x 32 q-rows
// (q-tile 256). 32x32x16 MFMA, swapped QK^T, in-register P transpose
// (cvt_pk + permlane32_swap). 4-deep K/V LDS buffers: ONE barrier per
// 2 k-tiles; global loads issued a full 2-tile group ahead of their
// ds_write, which is a further group ahead of the reads. s_setprio(1)
// wraps each MFMA cluster (T5). XOR-swizzled LDS (16B-chunk ^= row&7).
__global__ __launch_bounds__(512, 4) void attn_kernel(
    const bf16* __restrict__ Q, const bf16* __restrict__ Kg,
    const bf16* __restrict__ VtG, bf16* __restrict__ O)
{
    // 64 (h,b) groups x 8 q-tiles; all q-tiles of a group on one XCD
    // (linear blockIdx round-robins XCDs: xcd = id & 7).
    const int id  = blockIdx.x;
    const int xcd = id & 7, j = id >> 3;
    const int qt  = j & 7;
    const int g   = xcd + 8 * (j >> 3);
    const int h   = g & 15, b = g >> 4;

    const int tid  = threadIdx.x;
    const int lane = tid & 63;
    const int wave = tid >> 6;
    const int l31  = lane & 31;
    const int hi   = lane >> 5;

    __shared__ bf16 Kt[4][64 * 64];   // K[kk][d], swizzled
    __shared__ bf16 Vt[4][64 * 64];   // V^T[d][kk], swizzled

    // Q B-fragments, resident whole kernel: lane holds Q[q=l31][d=f*16+hi*8+j]
    const long qrow = (long)(b * 2048 + qt * 256 + wave * 32 + l31);
    v8bf qB[4];
    #pragma unroll
    for (int f = 0; f < 4; f++)
        qB[f] = *(const v8bf*)(Q + qrow * D + h * 64 + f * 16 + hi * 8);

    const v16f z16 = {0.f,0.f,0.f,0.f,0.f,0.f,0.f,0.f,
                      0.f,0.f,0.f,0.f,0.f,0.f,0.f,0.f};
    v16f o_acc[2];
    o_acc[0] = z16; o_acc[1] = z16;
    float l0 = 0.f, l1 = 0.f;

    const int iR = tid >> 3;        // staging row 0..63
    const int c8 = tid & 7;         // 16B chunk 0..7
    const bf16* kLane = Kg  + (long)b * 2048 * D + h * 64 + c8 * 8 + (long)iR * D;
    const bf16* vLane = VtG + (long)(b * 16 + h) * 64 * 2048 + c8 * 8 + (long)iR * 2048;
    const int wOff = iR * 64 + ((c8 ^ (iR & 7)) * 8);   // swizzled write slot

    v8bf kp[2], vp[2];
    // tiles 0,1 -> regs -> bufs 0,1
    kp[0] = *(const v8bf*)(kLane); vp[0] = *(const v8bf*)(vLane);
    kLane += 64 * D; vLane += 64;
    kp[1] = *(const v8bf*)(kLane); vp[1] = *(const v8bf*)(vLane);
    kLane += 64 * D; vLane += 64;
    *(v8bf*)(&Kt[0][wOff]) = kp[0]; *(v8bf*)(&Vt[0][wOff]) = vp[0];
    *(v8bf*)(&Kt[1][wOff]) = kp[1]; *(v8bf*)(&Vt[1][wOff]) = vp[1];
    // tiles 2,3 -> regs
    kp[0] = *(const v8bf*)(kLane); vp[0] = *(const v8bf*)(vLane);
    kLane += 64 * D; vLane += 64;
    kp[1] = *(const v8bf*)(kLane); vp[1] = *(const v8bf*)(vLane);
    kLane += 64 * D; vLane += 64;

    auto compute = [&](const int bq) {
        #pragma unroll
        for (int ko = 0; ko < 2; ko++) {
            // S^T (32k x 32q) = K_sub * Q^T, contraction d=64 in 4 steps
            const int krow = ko * 32 + l31;
            const int ksw  = krow & 7;
            v8bf kA[4];
            #pragma unroll
            for (int f = 0; f < 4; f++)
                kA[f] = *(const v8bf*)(&Kt[bq][krow * 64 + (((2 * f + hi) ^ ksw) * 8)]);
            __builtin_amdgcn_s_setprio(1);
            v16f st = __builtin_amdgcn_mfma_f32_32x32x16_bf16(kA[0], qB[0], z16, 0, 0, 0);
            st = __builtin_amdgcn_mfma_f32_32x32x16_bf16(kA[1], qB[1], st, 0, 0, 0);
            st = __builtin_amdgcn_mfma_f32_32x32x16_bf16(kA[2], qB[2], st, 0, 0, 0);
            st = __builtin_amdgcn_mfma_f32_32x32x16_bf16(kA[3], qB[3], st, 0, 0, 0);
            __builtin_amdgcn_s_setprio(0);

            // p = exp2(s); accumulate l in two chains
            float p[16];
            #pragma unroll
            for (int r = 0; r < 16; r++) {
                p[r] = __builtin_amdgcn_exp2f(st[r]);
                if (r & 1) l1 += p[r]; else l0 += p[r];
            }

            // in-register transpose to PV A-frags + PV MFMA
            #pragma unroll
            for (int u = 0; u < 2; u++) {
                const int s = ko * 2 + u;          // k-step of 16 within tile
                u32 a0, a1, b0, b1;
                asm("v_cvt_pk_bf16_f32 %0, %1, %2" : "=v"(a0) : "v"(p[u*8+0]), "v"(p[u*8+1]));
                asm("v_cvt_pk_bf16_f32 %0, %1, %2" : "=v"(a1) : "v"(p[u*8+2]), "v"(p[u*8+3]));
                asm("v_cvt_pk_bf16_f32 %0, %1, %2" : "=v"(b0) : "v"(p[u*8+4]), "v"(p[u*8+5]));
                asm("v_cvt_pk_bf16_f32 %0, %1, %2" : "=v"(b1) : "v"(p[u*8+6]), "v"(p[u*8+7]));
                asm("v_permlane32_swap_b32 %0, %1" : "+v"(a0), "+v"(b0));
                asm("v_permlane32_swap_b32 %0, %1" : "+v"(a1), "+v"(b1));
                v4u w; w[0] = a0; w[1] = a1; w[2] = b0; w[3] = b1;
                const v8bf pa = __builtin_bit_cast(v8bf, w);
                const int vsw = (l31 & 7);
                v8bf vb0 = *(const v8bf*)(&Vt[bq][(l31)      * 64 + (((2 * s + hi) ^ vsw) * 8)]);
                v8bf vb1 = *(const v8bf*)(&Vt[bq][(32 + l31) * 64 + (((2 * s + hi) ^ vsw) * 8)]);
                __builtin_amdgcn_s_setprio(1);
                o_acc[0] = __builtin_amdgcn_mfma_f32_32x32x16_bf16(pa, vb0, o_acc[0], 0, 0, 0);
                o_acc[1] = __builtin_amdgcn_mfma_f32_32x32x16_bf16(pa, vb1, o_acc[1], 0, 0, 0);
                __builtin_amdgcn_s_setprio(0);
            }
        }
    };

    for (int gg = 0; gg < 16; ++gg) {
        const int cb = (gg & 1) * 2;   // compute bufs cb, cb+1; write cb^2, cb^2+1
        __syncthreads();               // publishes bufs cb,cb+1; frees cb^2,cb^2+1

        if (gg < 15) {
            *(v8bf*)(&Kt[cb ^ 2][wOff])       = kp[0];
            *(v8bf*)(&Vt[cb ^ 2][wOff])       = vp[0];
            *(v8bf*)(&Kt[(cb ^ 2) + 1][wOff]) = kp[1];
            *(v8bf*)(&Vt[(cb ^ 2) + 1][wOff]) = vp[1];
        }
        if (gg < 14) {
            kp[0] = *(const v8bf*)(kLane); vp[0] = *(const v8bf*)(vLane);
            kLane += 64 * D; vLane += 64;
            kp[1] = *(const v8bf*)(kLane); vp[1] = *(const v8bf*)(vLane);
            kLane += 64 * D; vLane += 64;
        }

        compute(cb);
        compute(cb + 1);
    }

    // l per q-row: lane (l31,hi) holds the hi-half partial; combine halves.
    float l_acc = l0 + l1;
    l_acc += __shfl_xor(l_acc, 32);

    const long obase = (long)(b * 2048 + qt * 256 + wave * 32);
    #pragma unroll
    for (int r = 0; r < 16; r++) {
        const int qp = (r & 3) + 8 * (r >> 2) + 4 * hi;   // C row for reg r
        const float inv = 1.f / __shfl(l_acc, qp);
        O[(obase + qp) * D + h * 64 + l31]      = (bf16)(o_acc[0][r] * inv);
        O[(obase + qp) * D + h * 64 + 32 + l31] = (bf16)(o_acc[1][r] * inv);
    }
}

// ------------------------------------------------------------------ LN ----
__global__ __launch_bounds__(256) void ln_kernel(
    const float* __restrict__ g, const float* __restrict__ beta,
    float* __restrict__ out)
{
    const int row = blockIdx.x;
    const int t = threadIdx.x;
    const int lane = t & 63, wave = t >> 6;
    const long base = (long)row * D + t * 4;

    float4 yv = *(const float4*)(out + base);
    float y0 = yv.x, y1 = yv.y, y2 = yv.z, y3 = yv.w;
    float s1 = y0 + y1 + y2 + y3;
    float s2 = y0*y0 + y1*y1 + y2*y2 + y3*y3;
    #pragma unroll
    for (int off = 1; off < 64; off <<= 1) {
        s1 += __shfl_xor(s1, off);
        s2 += __shfl_xor(s2, off);
    }
    __shared__ float r1[4], r2[4];
    if (lane == 0) { r1[wave] = s1; r2[wave] = s2; }
    __syncthreads();
    float S1 = r1[0] + r1[1] + r1[2] + r1[3];
    float S2 = r2[0] + r2[1] + r2[2] + r2[3];
    float mu  = S1 * (1.f / 1024.f);
    float var = S2 * (1.f / 1024.f) - mu * mu;
    float rsd = rsqrtf(var + 1e-5f);

    float4 gv = *(const float4*)(g + t * 4);
    float4 bv = *(const float4*)(beta + t * 4);
    float4 o;
    o.x = (y0 - mu) * rsd * gv.x + bv.x;
    o.y = (y1 - mu) * rsd * gv.y + bv.y;
    o.z = (y2 - mu) * rsd * gv.z + bv.z;
    o.w = (y3 - mu) * rsd * gv.w + bv.w;
    *(float4*)(out + base) = o;
}

// ---------------------------------------------------------------- launch --
extern "C" void kernel_launch(void* const* d_in, const int* in_sizes, int n_in,
                              void* d_out, int out_size, void* d_ws, size_t ws_size,
                              hipStream_t stream)
{
    const float* x   = (const float*)d_in[0];
    const float* wq  = (const float*)d_in[1];
    const float* wk  = (const float*)d_in[2];
    const float* wv  = (const float*)d_in[3];
    const float* wo  = (const float*)d_in[4];
    const float* bo  = (const float*)d_in[5];
    const float* lng = (const float*)d_in[6];
    const float* lnb = (const float*)d_in[7];
    float* out = (float*)d_out;

    char* ws = (char*)d_ws;
    bf16* xb  = (bf16*)(ws);                            // 16 MiB
    bf16* wqb = (bf16*)(ws + (size_t)16 * 1024 * 1024); // 4 x 2 MiB
    bf16* wkb = wqb + 1024 * 1024;
    bf16* wvb = wkb + 1024 * 1024;
    bf16* wob = wvb + 1024 * 1024;
    bf16* Qb  = (bf16*)(ws + (size_t)24 * 1024 * 1024); // 4 x 16 MiB
    bf16* Kb  = Qb + (size_t)ROWS * D;
    bf16* VtG = Kb + (size_t)ROWS * D;                  // V transposed [b][h][d][s]
    bf16* Ab  = VtG + (size_t)ROWS * D;                 // total 88 MiB

    cast_all<<<12288, 256, 0, stream>>>(x, wq, wk, wv, wo,
                                        xb, wqb, wkb, wvb, wob);

    dim3 gqkv(D / TILE, ROWS / TILE, 3);
    gemm_bt<0><<<gqkv, 256, 0, stream>>>(xb, wqb, wkb, wvb, Qb, Kb, VtG,
                                         nullptr, nullptr, nullptr);

    attn_kernel<<<dim3(512, 1, 1), 512, 0, stream>>>(Qb, Kb, VtG, Ab);

    dim3 gout(D / TILE, ROWS / TILE, 1);
    gemm_bt<1><<<gout, 256, 0, stream>>>(Ab, wob, nullptr, nullptr,
                                         nullptr, nullptr, nullptr, out, bo, x);

    ln_kernel<<<8192, 256, 0, stream>>>(lng, lnb, out);
}